// Round 4
// baseline (223.486 us; speedup 1.0000x reference)
//
#include <hip/hip_runtime.h>
#include <stdint.h>

#define NN 8192      // nodes per batch
#define EE 8191      // edges per batch
#define AD 256       // ADIM
#define BB 16        // batch

typedef unsigned short u16;
typedef short bf16x8 __attribute__((ext_vector_type(8)));
typedef float f32x4 __attribute__((ext_vector_type(4)));
typedef u16 u16x8 __attribute__((ext_vector_type(8)));

__device__ __forceinline__ u16 f2bf(float f) {
  unsigned u = __builtin_bit_cast(unsigned, f);
  u = u + 0x7fffu + ((u >> 16) & 1u);   // RNE
  return (u16)(u >> 16);
}

// ---------------------------------------------------------------------------
// prep_ma (merged): per block o:
//   Ma[s=tap*8+ac*2+ks][o][32] = bf16(sum_c K_a[o,c,tap] * W2[c, a]),
//     a = ac*64 + ks*32 + jj   (contiguous 64B rows -> coalesced gemm loads)
//   bk[tap][o] = sum_c K_a[o,c,tap]*b2[c];  bias_all[o] = b_a[o] + sum_t bk
//   blocks 0..7 additionally: Mv[k][o][i] = sum_c K_v[o,c,k]*W_v[c,i]
// grid = 256, block = 256.
// ---------------------------------------------------------------------------
__global__ __launch_bounds__(256) void prep_ma(const float* __restrict__ W2,
                                               const float* __restrict__ b2,
                                               const float* __restrict__ K_a,
                                               const float* __restrict__ b_a,
                                               const float* __restrict__ W_v,
                                               const float* __restrict__ K_v,
                                               u16* __restrict__ Ma,
                                               float* __restrict__ bk,
                                               float* __restrict__ bias_all,
                                               float* __restrict__ Mv) {
  __shared__ float ka[256][4];
  __shared__ float b2s[256];
  __shared__ float red[4];
  const int tid = threadIdx.x;
  const int o = blockIdx.x;
  const float4 kv = ((const float4*)K_a)[(size_t)o * 256 + tid];
  ka[tid][0] = kv.x; ka[tid][1] = kv.y; ka[tid][2] = kv.z; ka[tid][3] = kv.w;
  b2s[tid] = b2[tid];
  __syncthreads();
  float acc[4] = {0.f, 0.f, 0.f, 0.f};
  for (int c = 0; c < 256; ++c) {
    const float w = W2[(c << 8) + tid];
    acc[0] += ka[c][0] * w; acc[1] += ka[c][1] * w;
    acc[2] += ka[c][2] * w; acc[3] += ka[c][3] * w;
  }
  const int ac = tid >> 6, ks = (tid >> 5) & 1, jj = tid & 31;
#pragma unroll
  for (int t = 0; t < 4; ++t)
    Ma[((size_t)((t * 8 + ac * 2 + ks) * 256 + o)) * 32 + jj] = f2bf(acc[t]);
  if (tid < 4) {
    float s = 0.f;
    for (int c = 0; c < 256; ++c) s += ka[c][tid] * b2s[c];
    bk[tid * 256 + o] = s;
    red[tid] = s;
  }
  __syncthreads();
  if (tid == 0) bias_all[o] = b_a[o] + red[0] + red[1] + red[2] + red[3];
  if (blockIdx.x < 8) {
    const int idx2 = blockIdx.x * 256 + tid;   // 2048 entries: [k][ov][i]
    const int k = idx2 >> 9, rem = idx2 & 511, ov = rem >> 2, i = rem & 3;
    float a2 = 0.f;
    for (int c = 0; c < 128; ++c)
      a2 += K_v[(size_t)((ov << 7) + c) * 4 + k] * W_v[(c << 2) + i];
    Mv[idx2] = a2;
  }
}

// ---------------------------------------------------------------------------
// gemm_a (fused h + fixup): a_out[n,o] = sum M[tap][o][a]*h[n+tap-2,a] + bias.
// Block: 128 nodes x 256 outs, 8 waves (2x4), wave = 64x64, mfma 16x16x32.
// h tile computed in-kernel into LDS (131 x 528B). B streamed global->VGPR
// with MANUAL 2-deep ping-pong prefetch (unroll 1) -> bounded reg pressure,
// guaranteed 1-step lookahead. No barriers in K-loop. 2 blocks/CU.
// grid = 16*64, block = 512.
// ---------------------------------------------------------------------------
#define MM(Bf, Af, C) __builtin_amdgcn_mfma_f32_16x16x32_bf16((Bf), (Af), (C), 0, 0, 0)

__global__ __launch_bounds__(512, 4) void gemm_a(const float* __restrict__ p0,
                                                 const float* __restrict__ p1,
                                                 const float* __restrict__ W1,
                                                 const float* __restrict__ b1,
                                                 const u16* __restrict__ Ma,
                                                 const float* __restrict__ bias_all,
                                                 const float* __restrict__ bk,
                                                 float* __restrict__ out) {
  __shared__ __align__(16) char hs[131 * 528];   // 69,168 B
  __shared__ float nrm[131][4];
  const int tid = threadIdx.x;
  const int lane = tid & 63;
  const int wid = tid >> 6;
  const int wm = wid >> 2, wn = wid & 3;
  const int b = blockIdx.x >> 6;
  const int n0 = (blockIdx.x & 63) * 128;
  const int lhi = lane >> 4;   // 0..3
  const int llo = lane & 15;   // 0..15

  // --- norms for rows 0..130 (edge e = n0 + rr - 2) ---
  const size_t pbase = (size_t)b * NN * 3;
  for (int idx = tid; idx < 524; idx += 512) {
    const int rr = idx >> 2, i = idx & 3;
    const int e = n0 + rr - 2;
    float v = 0.f;
    if (e >= 0 && e < EE) {
      const float* P0 = p0 + pbase;
      const float* P1 = p1 + pbase;
      const float* hi = (i == 0) ? P0 + (size_t)(e + 1) * 3
                      : (i == 1) ? P1 + (size_t)(e + 1) * 3
                      : (i == 2) ? P1 + (size_t)e * 3
                                 : P1 + (size_t)(e + 1) * 3;
      const float* lo = (i == 0) ? P0 + (size_t)e * 3
                      : (i == 1) ? P1 + (size_t)e * 3
                      : (i == 2) ? P0 + (size_t)(e + 1) * 3
                                 : P0 + (size_t)e * 3;
      const float dx = hi[0] - lo[0], dy = hi[1] - lo[1], dz = hi[2] - lo[2];
      v = sqrtf(dx * dx + dy * dy + dz * dz);
    }
    nrm[rr][i] = v;
  }
  __syncthreads();

  // --- h tile: h[rr][a] = LeakyReLU(b1 + nrm . W1) as bf16, zero pad rows ---
  {
    const int g8 = tid & 31;      // a-group (cols 8*g8 .. 8*g8+7)
    const int strip = tid >> 5;   // row strip 0..15
    float w1r[8][4], b1r[8];
    const float4* W14 = (const float4*)W1;
#pragma unroll
    for (int j = 0; j < 8; ++j) {
      const float4 w = W14[g8 * 8 + j];
      w1r[j][0] = w.x; w1r[j][1] = w.y; w1r[j][2] = w.z; w1r[j][3] = w.w;
      b1r[j] = b1[g8 * 8 + j];
    }
    for (int rr = strip; rr < 131; rr += 16) {
      const int e = n0 + rr - 2;
      const bool valid = (e >= 0) && (e < EE);
      const float nA = nrm[rr][0], nB = nrm[rr][1], nC = nrm[rr][2], nD = nrm[rr][3];
      u16x8 pack;
#pragma unroll
      for (int j = 0; j < 8; ++j) {
        float v = b1r[j] + nA * w1r[j][0] + nB * w1r[j][1] +
                  nC * w1r[j][2] + nD * w1r[j][3];
        v = (v >= 0.f) ? v : 0.2f * v;
        pack[j] = valid ? f2bf(v) : (u16)0;
      }
      *(u16x8*)(hs + rr * 528 + g8 * 16) = pack;
    }
  }
  __syncthreads();

  // --- K-loop: 32 steps, s = tap*8 + ac*2 + ks; manual 2-deep B prefetch ---
  const f32x4 zero = {0.f, 0.f, 0.f, 0.f};
  f32x4 acc[4][4];
#pragma unroll
  for (int m = 0; m < 4; ++m)
#pragma unroll
    for (int nf = 0; nf < 4; ++nf) acc[m][nf] = zero;

  const char* mb = (const char*)Ma + (size_t)(wn * 64 + llo) * 64 + (size_t)lhi * 16;
  const char* ha = hs + (wm * 64 + llo) * 528;

  bf16x8 pA0, pA1, pA2, pA3, pB0, pB1, pB2, pB3;
  pA0 = *(const bf16x8*)(mb);
  pA1 = *(const bf16x8*)(mb + 1024);
  pA2 = *(const bf16x8*)(mb + 2048);
  pA3 = *(const bf16x8*)(mb + 3072);

#pragma unroll 1
  for (int s = 0; s < 32; s += 2) {
    // prefetch s+1 -> set B
    {
      const char* bp = mb + (size_t)(s + 1) * 16384;
      pB0 = *(const bf16x8*)(bp);
      pB1 = *(const bf16x8*)(bp + 1024);
      pB2 = *(const bf16x8*)(bp + 2048);
      pB3 = *(const bf16x8*)(bp + 3072);
    }
    const int tap = s >> 3;
    const int cAe = ((s >> 1) & 3) * 128 + lhi * 16;   // even step (ks=0)
    {
      const int ro = tap * 528 + cAe;
      bf16x8 af0 = *(const bf16x8*)(ha + ro);
      bf16x8 af1 = *(const bf16x8*)(ha + 16 * 528 + ro);
      bf16x8 af2 = *(const bf16x8*)(ha + 32 * 528 + ro);
      bf16x8 af3 = *(const bf16x8*)(ha + 48 * 528 + ro);
      acc[0][0] = MM(pA0, af0, acc[0][0]); acc[1][0] = MM(pA0, af1, acc[1][0]);
      acc[2][0] = MM(pA0, af2, acc[2][0]); acc[3][0] = MM(pA0, af3, acc[3][0]);
      acc[0][1] = MM(pA1, af0, acc[0][1]); acc[1][1] = MM(pA1, af1, acc[1][1]);
      acc[2][1] = MM(pA1, af2, acc[2][1]); acc[3][1] = MM(pA1, af3, acc[3][1]);
      acc[0][2] = MM(pA2, af0, acc[0][2]); acc[1][2] = MM(pA2, af1, acc[1][2]);
      acc[2][2] = MM(pA2, af2, acc[2][2]); acc[3][2] = MM(pA2, af3, acc[3][2]);
      acc[0][3] = MM(pA3, af0, acc[0][3]); acc[1][3] = MM(pA3, af1, acc[1][3]);
      acc[2][3] = MM(pA3, af2, acc[2][3]); acc[3][3] = MM(pA3, af3, acc[3][3]);
    }
    // prefetch s+2 -> set A (clamped to stay in Ma; redundant last load ok)
    {
      const int sp = (s + 2 < 32) ? (s + 2) : 31;
      const char* bp = mb + (size_t)sp * 16384;
      pA0 = *(const bf16x8*)(bp);
      pA1 = *(const bf16x8*)(bp + 1024);
      pA2 = *(const bf16x8*)(bp + 2048);
      pA3 = *(const bf16x8*)(bp + 3072);
    }
    {
      const int ro = tap * 528 + cAe + 64;   // odd step (ks=1), same tap
      bf16x8 af0 = *(const bf16x8*)(ha + ro);
      bf16x8 af1 = *(const bf16x8*)(ha + 16 * 528 + ro);
      bf16x8 af2 = *(const bf16x8*)(ha + 32 * 528 + ro);
      bf16x8 af3 = *(const bf16x8*)(ha + 48 * 528 + ro);
      acc[0][0] = MM(pB0, af0, acc[0][0]); acc[1][0] = MM(pB0, af1, acc[1][0]);
      acc[2][0] = MM(pB0, af2, acc[2][0]); acc[3][0] = MM(pB0, af3, acc[3][0]);
      acc[0][1] = MM(pB1, af0, acc[0][1]); acc[1][1] = MM(pB1, af1, acc[1][1]);
      acc[2][1] = MM(pB1, af2, acc[2][1]); acc[3][1] = MM(pB1, af3, acc[3][1]);
      acc[0][2] = MM(pB2, af0, acc[0][2]); acc[1][2] = MM(pB2, af1, acc[1][2]);
      acc[2][2] = MM(pB2, af2, acc[2][2]); acc[3][2] = MM(pB2, af3, acc[3][2]);
      acc[0][3] = MM(pB3, af0, acc[0][3]); acc[1][3] = MM(pB3, af1, acc[1][3]);
      acc[2][3] = MM(pB3, af2, acc[2][3]); acc[3][3] = MM(pB3, af3, acc[3][3]);
    }
  }

  // --- epilogue: D row = o (lhi*4+j), col = node (llo); fixup folded ---
#pragma unroll
  for (int m = 0; m < 4; ++m) {
    const int node = n0 + wm * 64 + m * 16 + llo;
    float* orow = out + ((size_t)b * NN + node) * AD;
    const bool edge = (node <= 1) | (node >= NN - 2);
#pragma unroll
    for (int nf = 0; nf < 4; ++nf) {
      const int o0 = wn * 64 + nf * 16 + lhi * 4;
      float bx = bias_all[o0], by = bias_all[o0 + 1],
            bz = bias_all[o0 + 2], bw = bias_all[o0 + 3];
      if (edge) {
        const float* k0 = bk + o0;
        const float* k1 = bk + 256 + o0;
        const float* k2 = bk + 512 + o0;
        const float* k3 = bk + 768 + o0;
        if (node == 0) {
          bx -= k0[0] + k1[0]; by -= k0[1] + k1[1];
          bz -= k0[2] + k1[2]; bw -= k0[3] + k1[3];
        } else if (node == 1) {
          bx -= k0[0]; by -= k0[1]; bz -= k0[2]; bw -= k0[3];
        } else if (node == NN - 2) {
          bx -= k3[0]; by -= k3[1]; bz -= k3[2]; bw -= k3[3];
        } else {
          bx -= k2[0] + k3[0]; by -= k2[1] + k3[1];
          bz -= k2[2] + k3[2]; bw -= k2[3] + k3[3];
        }
      }
      float4 st;
      st.x = acc[m][nf][0] + bx;
      st.y = acc[m][nf][1] + by;
      st.z = acc[m][nf][2] + bz;
      st.w = acc[m][nf][3] + bw;
      *(float4*)(orow + o0) = st;
    }
  }
}

// ---------------------------------------------------------------------------
// vec_path: v_out[n,o,d] = sum_{k,i} Mv[k][o][i] * vec(e=n+k-2, i, d)
// ---------------------------------------------------------------------------
__global__ __launch_bounds__(256) void vec_path(const float* __restrict__ p0,
                                                const float* __restrict__ p1,
                                                const float* __restrict__ Mv,
                                                float* __restrict__ out) {
  __shared__ float MvS[2048];
  __shared__ __align__(16) float ob[32 * 384];
  const int tid = threadIdx.x;
  const int b = blockIdx.x >> 8;
  const int n0 = (blockIdx.x & 255) * 32;
  for (int idx = tid; idx < 2048; idx += 256) MvS[idx] = Mv[idx];
  __syncthreads();
  const int nl = tid >> 3, q = tid & 7;
  const int n = n0 + nl;
  const size_t pbase = (size_t)b * NN * 3;
  float s[4][4][3];
#pragma unroll
  for (int k = 0; k < 4; ++k) {
    const int e = n + k - 2;
    if (e >= 0 && e < EE) {
      const float* A0 = p0 + pbase + (size_t)e * 3;
      const float* A1 = p0 + pbase + (size_t)(e + 1) * 3;
      const float* C0 = p1 + pbase + (size_t)e * 3;
      const float* C1 = p1 + pbase + (size_t)(e + 1) * 3;
#pragma unroll
      for (int d = 0; d < 3; ++d) {
        const float a0v = A0[d], a1v = A1[d], c0v = C0[d], c1v = C1[d];
        s[k][0][d] = a1v - a0v;
        s[k][1][d] = c1v - c0v;
        s[k][2][d] = c0v - a1v;
        s[k][3][d] = c1v - a0v;
      }
    } else {
#pragma unroll
      for (int i2 = 0; i2 < 4; ++i2)
#pragma unroll
        for (int d = 0; d < 3; ++d) s[k][i2][d] = 0.f;
    }
  }
  for (int oi = 0; oi < 16; ++oi) {
    const int o = q * 16 + oi;
    float r0 = 0.f, r1 = 0.f, r2 = 0.f;
#pragma unroll
    for (int k = 0; k < 4; ++k) {
      const float* mp = &MvS[((k << 7) + o) << 2];
#pragma unroll
      for (int i2 = 0; i2 < 4; ++i2) {
        const float m = mp[i2];
        r0 += m * s[k][i2][0];
        r1 += m * s[k][i2][1];
        r2 += m * s[k][i2][2];
      }
    }
    ob[nl * 384 + o * 3 + 0] = r0;
    ob[nl * 384 + o * 3 + 1] = r1;
    ob[nl * 384 + o * 3 + 2] = r2;
  }
  __syncthreads();
  float4* dst = (float4*)(out + 33554432ULL + ((size_t)b * NN + n0) * 384);
  const float4* srcv = (const float4*)ob;
  for (int idx = tid; idx < 3072; idx += 256) dst[idx] = srcv[idx];
}

// ---------------------------------------------------------------------------
extern "C" void kernel_launch(void* const* d_in, const int* in_sizes, int n_in,
                              void* d_out, int out_size, void* d_ws, size_t ws_size,
                              hipStream_t stream) {
  const float* pos_0 = (const float*)d_in[0];
  const float* pos_1 = (const float*)d_in[1];
  const float* W_v = (const float*)d_in[2];
  const float* W1 = (const float*)d_in[3];
  const float* b1 = (const float*)d_in[4];
  const float* W2 = (const float*)d_in[5];
  const float* b2 = (const float*)d_in[6];
  const float* K_a = (const float*)d_in[7];
  const float* b_a = (const float*)d_in[8];
  const float* K_v = (const float*)d_in[9];
  float* out = (float*)d_out;
  char* ws = (char*)d_ws;

  const size_t MA_BYTES = (size_t)32 * 256 * 32 * 2;    // 524,288
  u16* Ma = (u16*)(ws);
  float* bk = (float*)(ws + MA_BYTES);
  float* bias_all = (float*)(ws + MA_BYTES + 4096);
  float* Mv = (float*)(ws + MA_BYTES + 4096 + 1024);

  prep_ma<<<dim3(256), dim3(256), 0, stream>>>(W2, b2, K_a, b_a, W_v, K_v,
                                               Ma, bk, bias_all, Mv);
  gemm_a<<<dim3(1024), dim3(512), 0, stream>>>(pos_0, pos_1, W1, b1, Ma,
                                               bias_all, bk, out);
  vec_path<<<dim3(4096), dim3(256), 0, stream>>>(pos_0, pos_1, Mv, out);
}

// Round 5
// 207.937 us; speedup vs baseline: 1.0748x; 1.0748x over previous
//
#include <hip/hip_runtime.h>
#include <stdint.h>

#define NN 8192      // nodes per batch
#define EE 8191      // edges per batch
#define AD 256       // ADIM
#define BB 16        // batch

typedef unsigned short u16;
typedef short bf16x8 __attribute__((ext_vector_type(8)));
typedef float f32x4 __attribute__((ext_vector_type(4)));
typedef u16 u16x8 __attribute__((ext_vector_type(8)));

__device__ __forceinline__ u16 f2bf(float f) {
  unsigned u = __builtin_bit_cast(unsigned, f);
  u = u + 0x7fffu + ((u >> 16) & 1u);   // RNE
  return (u16)(u >> 16);
}

// ---------------------------------------------------------------------------
// prep_ma (merged): per block o:
//   Ma[s=tap*8+ac*2+ks][o][32] = bf16(sum_c K_a[o,c,tap] * W2[c, a]),
//     a = ac*64 + ks*32 + jj   (contiguous 64B rows -> coalesced gemm loads)
//   bk[tap][o] = sum_c K_a[o,c,tap]*b2[c];  bias_all[o] = b_a[o] + sum_t bk
//   blocks 0..7 additionally: Mv[k][o][i] = sum_c K_v[o,c,k]*W_v[c,i]
// grid = 256, block = 256.
// ---------------------------------------------------------------------------
__global__ __launch_bounds__(256) void prep_ma(const float* __restrict__ W2,
                                               const float* __restrict__ b2,
                                               const float* __restrict__ K_a,
                                               const float* __restrict__ b_a,
                                               const float* __restrict__ W_v,
                                               const float* __restrict__ K_v,
                                               u16* __restrict__ Ma,
                                               float* __restrict__ bk,
                                               float* __restrict__ bias_all,
                                               float* __restrict__ Mv) {
  __shared__ float ka[256][4];
  __shared__ float b2s[256];
  __shared__ float red[4];
  const int tid = threadIdx.x;
  const int o = blockIdx.x;
  const float4 kv = ((const float4*)K_a)[(size_t)o * 256 + tid];
  ka[tid][0] = kv.x; ka[tid][1] = kv.y; ka[tid][2] = kv.z; ka[tid][3] = kv.w;
  b2s[tid] = b2[tid];
  __syncthreads();
  float acc[4] = {0.f, 0.f, 0.f, 0.f};
  for (int c = 0; c < 256; ++c) {
    const float w = W2[(c << 8) + tid];
    acc[0] += ka[c][0] * w; acc[1] += ka[c][1] * w;
    acc[2] += ka[c][2] * w; acc[3] += ka[c][3] * w;
  }
  const int ac = tid >> 6, ks = (tid >> 5) & 1, jj = tid & 31;
#pragma unroll
  for (int t = 0; t < 4; ++t)
    Ma[((size_t)((t * 8 + ac * 2 + ks) * 256 + o)) * 32 + jj] = f2bf(acc[t]);
  if (tid < 4) {
    float s = 0.f;
    for (int c = 0; c < 256; ++c) s += ka[c][tid] * b2s[c];
    bk[tid * 256 + o] = s;
    red[tid] = s;
  }
  __syncthreads();
  if (tid == 0) bias_all[o] = b_a[o] + red[0] + red[1] + red[2] + red[3];
  if (blockIdx.x < 8) {
    const int idx2 = blockIdx.x * 256 + tid;   // 2048 entries: [k][ov][i]
    const int k = idx2 >> 9, rem = idx2 & 511, ov = rem >> 2, i = rem & 3;
    float a2 = 0.f;
    for (int c = 0; c < 128; ++c)
      a2 += K_v[(size_t)((ov << 7) + c) * 4 + k] * W_v[(c << 2) + i];
    Mv[idx2] = a2;
  }
}

// ---------------------------------------------------------------------------
// gemm_a (fused h + fixup): a_out[n,o] = sum M[tap][o][a]*h[n+tap-2,a] + bias.
// Block: 256 nodes x 256 outs, 8 waves (2x4), wave = 128 nodes x 64 o.
// Rationale (L2-BW bound): 4 B-frags now feed 32 MFMAs (was 16) -> per-CU L2
// demand ~26 B/cy vs ~56 capacity. h tile (259 x 528B = 137KB LDS) computed
// in-kernel; B streamed global->VGPR, 2-deep ping-pong; no K-loop barriers.
// grid = 16*32, block = 512, 1 block/CU (2 waves/SIMD), VGPR ~207 < 256.
// ---------------------------------------------------------------------------
#define MM(Bf, Af, C) __builtin_amdgcn_mfma_f32_16x16x32_bf16((Bf), (Af), (C), 0, 0, 0)

__global__ __launch_bounds__(512, 2) void gemm_a(const float* __restrict__ p0,
                                                 const float* __restrict__ p1,
                                                 const float* __restrict__ W1,
                                                 const float* __restrict__ b1,
                                                 const u16* __restrict__ Ma,
                                                 const float* __restrict__ bias_all,
                                                 const float* __restrict__ bk,
                                                 float* __restrict__ out) {
  __shared__ __align__(16) char hs[259 * 528];   // 136,752 B
  __shared__ float nrm[259][4];
  const int tid = threadIdx.x;
  const int lane = tid & 63;
  const int wid = tid >> 6;
  const int wm = wid >> 2, wn = wid & 3;   // wm 0..1, wn 0..3
  const int b = blockIdx.x >> 5;
  const int n0 = (blockIdx.x & 31) * 256;
  const int lhi = lane >> 4;   // 0..3
  const int llo = lane & 15;   // 0..15

  // --- norms for rows 0..258 (edge e = n0 + rr - 2) ---
  const size_t pbase = (size_t)b * NN * 3;
  for (int idx = tid; idx < 1036; idx += 512) {
    const int rr = idx >> 2, i = idx & 3;
    const int e = n0 + rr - 2;
    float v = 0.f;
    if (e >= 0 && e < EE) {
      const float* P0 = p0 + pbase;
      const float* P1 = p1 + pbase;
      const float* hi = (i == 0) ? P0 + (size_t)(e + 1) * 3
                      : (i == 1) ? P1 + (size_t)(e + 1) * 3
                      : (i == 2) ? P1 + (size_t)e * 3
                                 : P1 + (size_t)(e + 1) * 3;
      const float* lo = (i == 0) ? P0 + (size_t)e * 3
                      : (i == 1) ? P1 + (size_t)e * 3
                      : (i == 2) ? P0 + (size_t)(e + 1) * 3
                                 : P0 + (size_t)e * 3;
      const float dx = hi[0] - lo[0], dy = hi[1] - lo[1], dz = hi[2] - lo[2];
      v = sqrtf(dx * dx + dy * dy + dz * dz);
    }
    nrm[rr][i] = v;
  }
  __syncthreads();

  // --- h tile: h[rr][a] = LeakyReLU(b1 + nrm . W1) as bf16, zero pad rows ---
  {
    const int g8 = tid & 31;      // a-group (cols 8*g8 .. 8*g8+7)
    const int strip = tid >> 5;   // row strip 0..15
    float w1r[8][4], b1r[8];
    const float4* W14 = (const float4*)W1;
#pragma unroll
    for (int j = 0; j < 8; ++j) {
      const float4 w = W14[g8 * 8 + j];
      w1r[j][0] = w.x; w1r[j][1] = w.y; w1r[j][2] = w.z; w1r[j][3] = w.w;
      b1r[j] = b1[g8 * 8 + j];
    }
    for (int rr = strip; rr < 259; rr += 16) {
      const int e = n0 + rr - 2;
      const bool valid = (e >= 0) && (e < EE);
      const float nA = nrm[rr][0], nB = nrm[rr][1], nC = nrm[rr][2], nD = nrm[rr][3];
      u16x8 pack;
#pragma unroll
      for (int j = 0; j < 8; ++j) {
        float v = b1r[j] + nA * w1r[j][0] + nB * w1r[j][1] +
                  nC * w1r[j][2] + nD * w1r[j][3];
        v = (v >= 0.f) ? v : 0.2f * v;
        pack[j] = valid ? f2bf(v) : (u16)0;
      }
      *(u16x8*)(hs + rr * 528 + g8 * 16) = pack;
    }
  }
  __syncthreads();

  // --- K-loop: 32 steps, s = tap*8 + ac*2 + ks; manual 2-deep B prefetch ---
  const f32x4 zero = {0.f, 0.f, 0.f, 0.f};
  f32x4 acc[8][4];
#pragma unroll
  for (int m = 0; m < 8; ++m)
#pragma unroll
    for (int nf = 0; nf < 4; ++nf) acc[m][nf] = zero;

  const char* mb = (const char*)Ma + (size_t)(wn * 64 + llo) * 64 + (size_t)lhi * 16;
  const char* ha = hs + (wm * 128 + llo) * 528;

  bf16x8 pA0, pA1, pA2, pA3, pB0, pB1, pB2, pB3;
  pA0 = *(const bf16x8*)(mb);
  pA1 = *(const bf16x8*)(mb + 1024);
  pA2 = *(const bf16x8*)(mb + 2048);
  pA3 = *(const bf16x8*)(mb + 3072);

#pragma unroll 1
  for (int s = 0; s < 32; s += 2) {
    // prefetch s+1 -> set B
    {
      const char* bp = mb + (size_t)(s + 1) * 16384;
      pB0 = *(const bf16x8*)(bp);
      pB1 = *(const bf16x8*)(bp + 1024);
      pB2 = *(const bf16x8*)(bp + 2048);
      pB3 = *(const bf16x8*)(bp + 3072);
    }
    const int tap = s >> 3;
    const int cAe = ((s >> 1) & 3) * 128 + lhi * 16;   // even step (ks=0)
    {
      const int ro = tap * 528 + cAe;
#pragma unroll
      for (int m = 0; m < 8; ++m) {
        const bf16x8 af = *(const bf16x8*)(ha + m * 16 * 528 + ro);
        acc[m][0] = MM(pA0, af, acc[m][0]);
        acc[m][1] = MM(pA1, af, acc[m][1]);
        acc[m][2] = MM(pA2, af, acc[m][2]);
        acc[m][3] = MM(pA3, af, acc[m][3]);
      }
    }
    // prefetch s+2 -> set A (clamped to stay in Ma; redundant last load ok)
    {
      const int sp = (s + 2 < 32) ? (s + 2) : 31;
      const char* bp = mb + (size_t)sp * 16384;
      pA0 = *(const bf16x8*)(bp);
      pA1 = *(const bf16x8*)(bp + 1024);
      pA2 = *(const bf16x8*)(bp + 2048);
      pA3 = *(const bf16x8*)(bp + 3072);
    }
    {
      const int ro = tap * 528 + cAe + 64;   // odd step (ks=1), same tap
#pragma unroll
      for (int m = 0; m < 8; ++m) {
        const bf16x8 af = *(const bf16x8*)(ha + m * 16 * 528 + ro);
        acc[m][0] = MM(pB0, af, acc[m][0]);
        acc[m][1] = MM(pB1, af, acc[m][1]);
        acc[m][2] = MM(pB2, af, acc[m][2]);
        acc[m][3] = MM(pB3, af, acc[m][3]);
      }
    }
  }

  // --- epilogue: D row = o (lhi*4+j), col = node (llo); fixup folded ---
#pragma unroll
  for (int m = 0; m < 8; ++m) {
    const int node = n0 + wm * 128 + m * 16 + llo;
    float* orow = out + ((size_t)b * NN + node) * AD;
    const bool edge = (node <= 1) | (node >= NN - 2);
#pragma unroll
    for (int nf = 0; nf < 4; ++nf) {
      const int o0 = wn * 64 + nf * 16 + lhi * 4;
      float bx = bias_all[o0], by = bias_all[o0 + 1],
            bz = bias_all[o0 + 2], bw = bias_all[o0 + 3];
      if (edge) {
        const float* k0 = bk + o0;
        const float* k1 = bk + 256 + o0;
        const float* k2 = bk + 512 + o0;
        const float* k3 = bk + 768 + o0;
        if (node == 0) {
          bx -= k0[0] + k1[0]; by -= k0[1] + k1[1];
          bz -= k0[2] + k1[2]; bw -= k0[3] + k1[3];
        } else if (node == 1) {
          bx -= k0[0]; by -= k0[1]; bz -= k0[2]; bw -= k0[3];
        } else if (node == NN - 2) {
          bx -= k3[0]; by -= k3[1]; bz -= k3[2]; bw -= k3[3];
        } else {
          bx -= k2[0] + k3[0]; by -= k2[1] + k3[1];
          bz -= k2[2] + k3[2]; bw -= k2[3] + k3[3];
        }
      }
      float4 st;
      st.x = acc[m][nf][0] + bx;
      st.y = acc[m][nf][1] + by;
      st.z = acc[m][nf][2] + bz;
      st.w = acc[m][nf][3] + bw;
      *(float4*)(orow + o0) = st;
    }
  }
}

// ---------------------------------------------------------------------------
// vec_path: v_out[n,o,d] = sum_{k,i} Mv[k][o][i] * vec(e=n+k-2, i, d)
// ---------------------------------------------------------------------------
__global__ __launch_bounds__(256) void vec_path(const float* __restrict__ p0,
                                                const float* __restrict__ p1,
                                                const float* __restrict__ Mv,
                                                float* __restrict__ out) {
  __shared__ float MvS[2048];
  __shared__ __align__(16) float ob[32 * 384];
  const int tid = threadIdx.x;
  const int b = blockIdx.x >> 8;
  const int n0 = (blockIdx.x & 255) * 32;
  for (int idx = tid; idx < 2048; idx += 256) MvS[idx] = Mv[idx];
  __syncthreads();
  const int nl = tid >> 3, q = tid & 7;
  const int n = n0 + nl;
  const size_t pbase = (size_t)b * NN * 3;
  float s[4][4][3];
#pragma unroll
  for (int k = 0; k < 4; ++k) {
    const int e = n + k - 2;
    if (e >= 0 && e < EE) {
      const float* A0 = p0 + pbase + (size_t)e * 3;
      const float* A1 = p0 + pbase + (size_t)(e + 1) * 3;
      const float* C0 = p1 + pbase + (size_t)e * 3;
      const float* C1 = p1 + pbase + (size_t)(e + 1) * 3;
#pragma unroll
      for (int d = 0; d < 3; ++d) {
        const float a0v = A0[d], a1v = A1[d], c0v = C0[d], c1v = C1[d];
        s[k][0][d] = a1v - a0v;
        s[k][1][d] = c1v - c0v;
        s[k][2][d] = c0v - a1v;
        s[k][3][d] = c1v - a0v;
      }
    } else {
#pragma unroll
      for (int i2 = 0; i2 < 4; ++i2)
#pragma unroll
        for (int d = 0; d < 3; ++d) s[k][i2][d] = 0.f;
    }
  }
  for (int oi = 0; oi < 16; ++oi) {
    const int o = q * 16 + oi;
    float r0 = 0.f, r1 = 0.f, r2 = 0.f;
#pragma unroll
    for (int k = 0; k < 4; ++k) {
      const float* mp = &MvS[((k << 7) + o) << 2];
#pragma unroll
      for (int i2 = 0; i2 < 4; ++i2) {
        const float m = mp[i2];
        r0 += m * s[k][i2][0];
        r1 += m * s[k][i2][1];
        r2 += m * s[k][i2][2];
      }
    }
    ob[nl * 384 + o * 3 + 0] = r0;
    ob[nl * 384 + o * 3 + 1] = r1;
    ob[nl * 384 + o * 3 + 2] = r2;
  }
  __syncthreads();
  float4* dst = (float4*)(out + 33554432ULL + ((size_t)b * NN + n0) * 384);
  const float4* srcv = (const float4*)ob;
  for (int idx = tid; idx < 3072; idx += 256) dst[idx] = srcv[idx];
}

// ---------------------------------------------------------------------------
extern "C" void kernel_launch(void* const* d_in, const int* in_sizes, int n_in,
                              void* d_out, int out_size, void* d_ws, size_t ws_size,
                              hipStream_t stream) {
  const float* pos_0 = (const float*)d_in[0];
  const float* pos_1 = (const float*)d_in[1];
  const float* W_v = (const float*)d_in[2];
  const float* W1 = (const float*)d_in[3];
  const float* b1 = (const float*)d_in[4];
  const float* W2 = (const float*)d_in[5];
  const float* b2 = (const float*)d_in[6];
  const float* K_a = (const float*)d_in[7];
  const float* b_a = (const float*)d_in[8];
  const float* K_v = (const float*)d_in[9];
  float* out = (float*)d_out;
  char* ws = (char*)d_ws;

  const size_t MA_BYTES = (size_t)32 * 256 * 32 * 2;    // 524,288
  u16* Ma = (u16*)(ws);
  float* bk = (float*)(ws + MA_BYTES);
  float* bias_all = (float*)(ws + MA_BYTES + 4096);
  float* Mv = (float*)(ws + MA_BYTES + 4096 + 1024);

  prep_ma<<<dim3(256), dim3(256), 0, stream>>>(W2, b2, K_a, b_a, W_v, K_v,
                                               Ma, bk, bias_all, Mv);
  gemm_a<<<dim3(512), dim3(512), 0, stream>>>(pos_0, pos_1, W1, b1, Ma,
                                              bias_all, bk, out);
  vec_path<<<dim3(4096), dim3(256), 0, stream>>>(pos_0, pos_1, Mv, out);
}